// Round 6
// baseline (243.806 us; speedup 1.0000x reference)
//
#include <hip/hip_runtime.h>
#include <stdint.h>
#include <math.h>

// Problem: B=2, T=2048, H=16, hd=64, D=1024, 3D=3072
// I/O dtype: float32 (per reference). Internal MFMA pipeline: bf16.
// d_out: [out (2,2048,1024)] ++ [new_cache (2,2,2048,16,64)], fp32
// d_in: x, Wqkv, bqkv, Wout, bout (fp32), offset (int32)

typedef __bf16 bf16_t;
typedef bf16_t bf16x8 __attribute__((ext_vector_type(8)));
typedef float f32x4 __attribute__((ext_vector_type(4)));
typedef unsigned short ushort8_t __attribute__((ext_vector_type(8)));

__device__ __forceinline__ unsigned short f2bf(float f) {
    union { float f; unsigned int i; } v; v.f = f;
    unsigned int r = v.i + 0x7fffu + ((v.i >> 16) & 1u);
    return (unsigned short)(r >> 16);
}
__device__ __forceinline__ bf16x8 ld8(const unsigned short* p) {
    return *(const bf16x8*)p;
}
__device__ __forceinline__ void gload_lds16(const unsigned short* g, unsigned short* l) {
    __builtin_amdgcn_global_load_lds(
        (__attribute__((address_space(1))) void*)(g),
        (__attribute__((address_space(3))) void*)(l),
        16, 0, 0);
}
#define WAITN(n) asm volatile("s_waitcnt vmcnt(" #n ")" ::: "memory")

// ---------------- fp32 -> bf16 bulk convert (8 elems/thread) ----------------
__global__ void k_cvt(const float* __restrict__ in, unsigned short* __restrict__ out) {
    const int i = (blockIdx.x * 256 + threadIdx.x) * 8;
    float4 a = *(const float4*)&in[i];
    float4 b = *(const float4*)&in[i + 4];
    ushort8_t v;
    v[0] = f2bf(a.x); v[1] = f2bf(a.y); v[2] = f2bf(a.z); v[3] = f2bf(a.w);
    v[4] = f2bf(b.x); v[5] = f2bf(b.y); v[6] = f2bf(b.z); v[7] = f2bf(b.w);
    *(ushort8_t*)&out[i] = v;
}

// ---------------- RoPE cos/sin table: tab[t][i][2], t<2048, i<32 ----------------
__global__ void k_ropetab(float* __restrict__ tab, const int* __restrict__ offp) {
    int idx = blockIdx.x * blockDim.x + threadIdx.x;   // 65536 threads
    int t = idx >> 5, i = idx & 31;
    float off = (float)(*offp);
    float inv = powf(10000.0f, -(float)(2 * i) / 64.0f);
    float ang = ((float)t + off) * inv;
    float s, c;
    sincosf(ang, &s, &c);
    tab[idx * 2]     = c;
    tab[idx * 2 + 1] = s;
}

// ------- 64x64 tile transpose + downconvert: in fp32 [bz][R][C] -> out bf16 [bz][C][R] -------
__global__ void k_transposeF2B(const float* __restrict__ in,
                               unsigned short* __restrict__ out, int R, int C) {
    __shared__ __align__(16) float tile[64 * 68];
    const int bz = blockIdx.z;
    const size_t base = (size_t)bz * R * C;
    const int tR = blockIdx.y * 64, tC = blockIdx.x * 64;
    const int tid = threadIdx.x;
#pragma unroll
    for (int it = 0; it < 4; ++it) {
        int flat = (it * 256 + tid) * 4;
        int r = flat >> 6, c = flat & 63;
        *(float4*)&tile[r * 68 + c] =
            *(const float4*)&in[base + (size_t)(tR + r) * C + tC + c];
    }
    __syncthreads();
#pragma unroll
    for (int it = 0; it < 2; ++it) {
        int flat = (it * 256 + tid) * 8;
        int rr = flat >> 6, cc = flat & 63;
        ushort8_t v;
#pragma unroll
        for (int j = 0; j < 8; ++j) v[j] = f2bf(tile[(cc + j) * 68 + rr]);
        *(ushort8_t*)&out[base + (size_t)(tC + rr) * R + tR + cc] = v;
    }
}

// ---------------- batched bf16 64x64 tile transpose: in[bz][R][C] -> out[bz][C][R] ----------------
__global__ void k_transpose64(const unsigned short* __restrict__ in,
                              unsigned short* __restrict__ out, int R, int C) {
    __shared__ __align__(16) unsigned short tile[64 * 72];
    const int bz = blockIdx.z;
    const size_t base = (size_t)bz * R * C;
    const int tR = blockIdx.y * 64, tC = blockIdx.x * 64;
    const int tid = threadIdx.x;
#pragma unroll
    for (int it = 0; it < 2; ++it) {
        int flat = (it * 256 + tid) * 8;
        int r = flat >> 6, c = flat & 63;
        *(ushort8_t*)&tile[r * 72 + c] =
            *(const ushort8_t*)&in[base + (size_t)(tR + r) * C + tC + c];
    }
    __syncthreads();
#pragma unroll
    for (int it = 0; it < 2; ++it) {
        int flat = (it * 256 + tid) * 8;
        int rr = flat >> 6, cc = flat & 63;
        ushort8_t v;
#pragma unroll
        for (int j = 0; j < 8; ++j) v[j] = tile[(cc + j) * 72 + rr];
        *(ushort8_t*)&out[base + (size_t)(tC + rr) * R + tR + cc] = v;
    }
}

// ================= 256x256 MFMA GEMM, K=1024, BK=64, 8-wave, 8-phase schedule =================
// ROUND-6: SINGLE barrier per phase (was 2 -> 128 full 8-wave rendezvous per K-loop).
// Phase = { s_barrier; ds_reads; stage; lgkmcnt(0); sched_barrier; 16 MFMA; [vmcnt] }.
// Safety (verified pair-by-pair):
//  RAW: counted vmcnt(6) at END of p3/p7 (before the next barrier) forces the 8 oldest
//       loads = exactly the 2 slots read in the following 4 phases; every wave executes
//       its wait before the barrier that precedes the dependent reads -> cross-wave safe.
//       (Also fixes round-5's latent prologue race: W(6) now forces B(0,1) as well.)
//  WAR: each slot's re-stage issues after a barrier that all waves reach only after
//       their lgkmcnt(0)-completed reads of that slot (A-slot0: read p0/staged p1;
//       B-slot0: read p1/staged p2; slot1: p2,p3/p3,p4; slots2,3 symmetric).
// setprio REMOVED from the GEMM (m190: hurts lockstep GEMM; stays in attn per m191).
template <int EPI>
__global__ __launch_bounds__(512, 2) void k_gemm(
    const unsigned short* __restrict__ A,
    const unsigned short* __restrict__ Bt,
    const float* __restrict__ bias,
    const float* __restrict__ tab,
    unsigned short* __restrict__ oq,
    unsigned short* __restrict__ ok,
    unsigned short* __restrict__ ov,
    float* __restrict__ cache,
    float* __restrict__ outp)
{
    constexpr int K = 1024;
    __shared__ __align__(16) unsigned short lds[65536];   // 128 KiB
    unsigned short* lA = lds;                    // 4 slots x 8192 ushorts (16 KB)
    unsigned short* lB = lds + 32768;

    const int tid  = threadIdx.x;
    const int lane = tid & 63, w = tid >> 6;
    const int wr = w >> 2, wc = w & 3;           // 2 x 4 wave grid
    const int lrow = lane & 15, quad = lane >> 4;

    // --- T1: XCD-aware bijective swizzle (nwg % 8 == 0) ---
    const int gx  = gridDim.x;
    const int nwg = gx * gridDim.y;
    const int bid = blockIdx.y * gx + blockIdx.x;
    const int sw  = (bid & 7) * (nwg >> 3) + (bid >> 3);
    const int blockM = (sw / gx) * 256;
    const int blockN = (sw % gx) * 256;

    // --- staging: linear LDS dest, pre-swizzled global source (T2, rule #21) ---
    const int q8    = (lane & 7) ^ (lane >> 3);
    const int srow0 = ((w * 16 + (lane >> 3)) << 1) + ((q8 >> 2) & 1);
    const int scol  = (q8 & 3) * 8;
    const unsigned short* srcA = A  + (size_t)(blockM + srow0) * K + scol;
    const unsigned short* srcB = Bt + (size_t)(blockN + srow0) * K + scol;
    unsigned short* dA = lA + w * 1024;          // + slot*8192 at use
    unsigned short* dB = lB + w * 1024;

    // --- frag reads: same XOR on the read side -> conflict-free b128 ---
    const int rp   = lrow >> 1;
    const int swzu = ((((lane & 1) << 6) | (quad << 4)) ^ (rp << 4)) >> 1;

    f32x4 acc[8][4];
#pragma unroll
    for (int m = 0; m < 8; ++m)
#pragma unroll
        for (int n = 0; n < 4; ++n) acc[m][n] = (f32x4){0.f, 0.f, 0.f, 0.f};

#define STAGE_A(T, KH) do { \
        const unsigned short* s_ = srcA + (T) * 64 + (KH) * 32; \
        unsigned short* d_ = dA + (((2*(T)+(KH)) & 3) << 13); \
        gload_lds16(s_, d_); \
        gload_lds16(s_ + 16 * K, d_ + 512); } while (0)
#define STAGE_B(T, KH) do { \
        const unsigned short* s_ = srcB + (T) * 64 + (KH) * 32; \
        unsigned short* d_ = dB + (((2*(T)+(KH)) & 3) << 13); \
        gload_lds16(s_, d_); \
        gload_lds16(s_ + 16 * K, d_ + 512); } while (0)
#define RD_A(slot) do { \
        _Pragma("unroll") \
        for (int m = 0; m < 8; ++m) \
            aA[m] = ld8(&lA[((slot) << 13) + (wr * 64 + m * 8 + rp) * 64 + swzu]); } while (0)
#define RD_B(slot, nh) do { \
        _Pragma("unroll") \
        for (int nl = 0; nl < 2; ++nl) \
            bB[nl] = ld8(&lB[((slot) << 13) + (wc * 32 + (nh) * 16 + nl * 8 + rp) * 64 + swzu]); } while (0)
#define BAR __builtin_amdgcn_s_barrier()
#define LGKSB do { \
        asm volatile("s_waitcnt lgkmcnt(0)" ::: "memory"); \
        __builtin_amdgcn_sched_barrier(0); } while (0)
#define MFMA16(nh) do { \
        _Pragma("unroll") \
        for (int m = 0; m < 8; ++m) { \
            acc[m][(nh)*2+0] = __builtin_amdgcn_mfma_f32_16x16x32_bf16(aA[m], bB[0], acc[m][(nh)*2+0], 0, 0, 0); \
            acc[m][(nh)*2+1] = __builtin_amdgcn_mfma_f32_16x16x32_bf16(aA[m], bB[1], acc[m][(nh)*2+1], 0, 0, 0); } \
        } while (0)

    // prologue: 7 halves (14 loads), oldest-first; W(6) forces slots 0,1 completely
    STAGE_A(0, 0); STAGE_B(0, 0);
    STAGE_A(0, 1); STAGE_B(0, 1);
    STAGE_A(1, 0); STAGE_B(1, 0);
    STAGE_A(1, 1);
    WAITN(6);

    bf16x8 aA[8], bB[2];
    for (int i = 0; i < 7; ++i) {
        const int E = 2 * i, O = 2 * i + 1;
        BAR; RD_A(0); RD_B(0, 0); STAGE_B(O, 1);     LGKSB; MFMA16(0);            // p0
        BAR; RD_B(0, 1);          STAGE_A(E + 2, 0); LGKSB; MFMA16(1);            // p1
        BAR; RD_A(1); RD_B(1, 0); STAGE_B(E + 2, 0); LGKSB; MFMA16(0);            // p2
        BAR; RD_B(1, 1);          STAGE_A(E + 2, 1); LGKSB; MFMA16(1); WAITN(6);  // p3
        BAR; RD_A(2); RD_B(2, 0); STAGE_B(E + 2, 1); LGKSB; MFMA16(0);            // p4
        BAR; RD_B(2, 1);          STAGE_A(O + 2, 0); LGKSB; MFMA16(1);            // p5
        BAR; RD_A(3); RD_B(3, 0); STAGE_B(O + 2, 0); LGKSB; MFMA16(0);            // p6
        BAR; RD_B(3, 1);          STAGE_A(O + 2, 1); LGKSB; MFMA16(1); WAITN(6);  // p7
    }
    // tail iteration (E=14, O=15): only B(15,1) still to stage; drain at its p3
    BAR; RD_A(0); RD_B(0, 0); STAGE_B(15, 1); LGKSB; MFMA16(0);
    BAR; RD_B(0, 1);                          LGKSB; MFMA16(1);
    BAR; RD_A(1); RD_B(1, 0);                 LGKSB; MFMA16(0);
    BAR; RD_B(1, 1);                          LGKSB; MFMA16(1); WAITN(0);
    BAR; RD_A(2); RD_B(2, 0);                 LGKSB; MFMA16(0);
    BAR; RD_B(2, 1);                          LGKSB; MFMA16(1);
    BAR; RD_A(3); RD_B(3, 0);                 LGKSB; MFMA16(0);
    BAR; RD_B(3, 1);                          LGKSB; MFMA16(1);
#undef STAGE_A
#undef STAGE_B
#undef RD_A
#undef RD_B
#undef BAR
#undef LGKSB
#undef MFMA16

    // ---------------- epilogue ----------------
#pragma unroll
    for (int m = 0; m < 8; ++m) {
        const int rbase = blockM + wr * 128 + m * 16 + quad * 4;
#pragma unroll
        for (int n = 0; n < 4; ++n) {
            const int gcol = blockN + wc * 64 + n * 16 + lrow;
            const float bv = bias[gcol];
#pragma unroll
            for (int r = 0; r < 4; ++r) {
                const int row = rbase + r;
                float val = acc[m][n][r] + bv;
                if (EPI == 0) {
                    outp[(size_t)row * 1024 + gcol] = val;
                } else {
                    const int s = gcol >> 10;          // 0:q 1:k 2:v (uniform per block)
                    const int cn = gcol & 1023;
                    const int h = cn >> 6, d = cn & 63;
                    const int b = row >> 11, t = row & 2047;
                    if (s < 2) {  // RoPE; pair element is in the adjacent lane
                        const int ii = d >> 1;
                        const float cz = tab[t * 64 + 2 * ii];
                        const float sz = tab[t * 64 + 2 * ii + 1];
                        const float pv = __shfl_xor(val, 1);
                        val = (d & 1) ? (pv * sz + val * cz) : (val * cz - pv * sz);
                    }
                    const unsigned short r16 = f2bf(val);
                    const size_t bhtd = (((size_t)(b * 16 + h)) * 2048 + t) * 64 + d;
                    if (s == 0) {
                        oq[bhtd] = r16;
                    } else if (s == 1) {
                        ok[bhtd] = r16;
                        cache[(((size_t)(b * 2 + 0)) * 2048 + t) * 1024 + h * 64 + d] = val;
                    } else {
                        ov[bhtd] = r16;
                        cache[(((size_t)(b * 2 + 1)) * 2048 + t) * 1024 + h * 64 + d] = val;
                    }
                }
            }
        }
    }
}

// ================= out-projection GEMM: 64x64 tiles, m97-style, 1024 blocks =================
// (round-5 version, unchanged: TLP > schedule at this tiny 8.6 GF op)
__global__ __launch_bounds__(256) void k_gemm0(
    const unsigned short* __restrict__ A,    // ctx bf16 [4096][1024]
    const unsigned short* __restrict__ Bt,   // woutT bf16 [1024][1024]
    const float* __restrict__ bias,
    float* __restrict__ outp)                // fp32 [4096][1024]
{
    constexpr int K = 1024;
    __shared__ __align__(16) unsigned short lA[2][64 * 32];
    __shared__ __align__(16) unsigned short lB[2][64 * 32];
    const int tid = threadIdx.x;
    const int wave = tid >> 6, lane = tid & 63;
    const int lrow = lane & 15, quad = lane >> 4;
    const int waveM = wave >> 1, waveN = wave & 1;
    const int blockM = blockIdx.y * 64, blockN = blockIdx.x * 64;

    f32x4 acc[2][2];
#pragma unroll
    for (int i = 0; i < 2; ++i)
#pragma unroll
        for (int j = 0; j < 2; ++j) acc[i][j] = (f32x4){0.f, 0.f, 0.f, 0.f};

    const int srow = tid >> 2;           // (tid*8)>>5
    const int scol = (tid & 3) * 8;
    auto stage = [&](int k0, int bsel) {
        gload_lds16(&A[(size_t)(blockM + srow) * K + k0 + scol], &lA[bsel][tid * 8]);
        gload_lds16(&Bt[(size_t)(blockN + srow) * K + k0 + scol], &lB[bsel][tid * 8]);
    };

    stage(0, 0);
    int buf = 0;
    for (int k0 = 0; k0 < K; k0 += 32) {
        __syncthreads();   // staged buf visible; prev compute on buf^1 done
        if (k0 + 32 < K) stage(k0 + 32, buf ^ 1);
        bf16x8 af[2], bfr[2];
#pragma unroll
        for (int mt = 0; mt < 2; ++mt)
            af[mt] = ld8(&lA[buf][(waveM * 32 + mt * 16 + lrow) * 32 + quad * 8]);
#pragma unroll
        for (int nt = 0; nt < 2; ++nt)
            bfr[nt] = ld8(&lB[buf][(waveN * 32 + nt * 16 + lrow) * 32 + quad * 8]);
#pragma unroll
        for (int mt = 0; mt < 2; ++mt)
#pragma unroll
            for (int nt = 0; nt < 2; ++nt)
                acc[mt][nt] = __builtin_amdgcn_mfma_f32_16x16x32_bf16(
                    af[mt], bfr[nt], acc[mt][nt], 0, 0, 0);
        buf ^= 1;
    }

#pragma unroll
    for (int mt = 0; mt < 2; ++mt) {
        const int rbase = blockM + waveM * 32 + mt * 16 + quad * 4;
#pragma unroll
        for (int nt = 0; nt < 2; ++nt) {
            const int gcol = blockN + waveN * 32 + nt * 16 + lrow;
            const float bv = bias[gcol];
#pragma unroll
            for (int r = 0; r < 4; ++r)
                outp[(size_t)(rbase + r) * 1024 + gcol] = acc[mt][nt][r] + bv;
        }
    }
}

// ---------------- flash attention (causal), merged triangle pair, deep pipeline ----------------
// (round-5/round-3 version, unchanged: single barrier/iter, wait-before-barrier, setprio kept)
__global__ __launch_bounds__(512, 2) void k_attn(
    const unsigned short* __restrict__ qh,   // [B][H][T][64] bf16
    const unsigned short* __restrict__ kh,   // [B][H][T][64] bf16
    const unsigned short* __restrict__ vt,   // [B][H][64][T] bf16
    unsigned short* __restrict__ ctx)        // [B*T][1024]   bf16
{
    __shared__ __align__(16) unsigned short lK[4][64 * 64];
    __shared__ __align__(16) unsigned short lV[4][64 * 64];
    __shared__ __align__(16) unsigned short lP[8][32 * 68];
    const int tid = threadIdx.x;
    const int wave = tid >> 6, lane = tid & 63;
    const int lrow = lane & 15, quad = lane >> 4;
    const int sub = lane >> 3, g8 = lane & 7;
    const int grp = g8 ^ (sub & 7);
    const int pj = blockIdx.x;               // 0..7
    const int h = blockIdx.y, b = blockIdx.z;
    const unsigned short* Q  = qh + (size_t)(b * 16 + h) * 2048 * 64;
    const unsigned short* Kp = kh + (size_t)(b * 16 + h) * 2048 * 64;
    const unsigned short* Vt = vt + (size_t)(b * 16 + h) * 64 * 2048;

    const int grpq = wave >> 2;              // 0: long q-block, 1: short
    const int wv   = wave & 3;
    const int qb   = grpq ? pj : (15 - pj);
    const int qw   = qb * 128 + wv * 32;     // this wave's first q row
    const int nT   = 2 * (16 - pj);          // 64-col K/V tiles staged (covers both groups)

    bf16x8 bOnes;
#pragma unroll
    for (int j = 0; j < 8; ++j) bOnes[j] = (bf16_t)1.0f;

    // Q fragments, pre-scaled by 1/sqrt(64)=0.125 (exact in bf16)
    bf16x8 aQ[2][2];
#pragma unroll
    for (int mf = 0; mf < 2; ++mf)
#pragma unroll
        for (int ks = 0; ks < 2; ++ks) {
            bf16x8 t = ld8(&Q[(size_t)(qw + mf * 16 + lrow) * 64 + ks * 32 + quad * 8]);
#pragma unroll
            for (int j = 0; j < 8; ++j) t[j] = (bf16_t)((float)t[j] * 0.125f);
            aQ[mf][ks] = t;
        }

    f32x4 o[2][4];
#pragma unroll
    for (int mf = 0; mf < 2; ++mf)
#pragma unroll
        for (int i = 0; i < 4; ++i) o[mf][i] = (f32x4){0.f, 0.f, 0.f, 0.f};
    f32x4 lacc[2];
    lacc[0] = (f32x4){0.f, 0.f, 0.f, 0.f};
    lacc[1] = (f32x4){0.f, 0.f, 0.f, 0.f};

    // stage tile t into ring slot t&3 (2 issues/wave: 1 K chunk + 1 V chunk)
#define STAGE_T(t) do { \
        const int c_ = wave, s_ = (t) & 3; \
        gload_lds16(&Kp[(size_t)((t) * 64 + c_ * 8 + sub) * 64 + grp * 8], &lK[s_][c_ * 512]); \
        gload_lds16(&Vt[(size_t)(c_ * 8 + sub) * 2048 + (t) * 64 + grp * 8], &lV[s_][c_ * 512]); } while (0)

    STAGE_T(0);
    STAGE_T(1);

    for (int it = 0; it < nT; ++it) {
        if (it + 2 < nT) {
            STAGE_T(it + 2);
            WAITN(4);      // forces own tile-it pair; before barrier -> race-free
        } else if (it + 1 < nT) {
            WAITN(2);
        } else {
            WAITN(0);
        }
        __builtin_amdgcn_s_barrier();
        __builtin_amdgcn_sched_barrier(0);
        const int kt0 = it * 64;
        if (kt0 < qw + 32) {
            const unsigned short* lKb = lK[it & 3];
            const unsigned short* lVb = lV[it & 3];
            f32x4 s[2][4];
#pragma unroll
            for (int mf = 0; mf < 2; ++mf)
#pragma unroll
                for (int i = 0; i < 4; ++i) s[mf][i] = (f32x4){0.f, 0.f, 0.f, 0.f};
            __builtin_amdgcn_s_setprio(1);
#pragma unroll
            for (int nt = 0; nt < 4; ++nt) {
                const int row = nt * 16 + lrow;
#pragma unroll
                for (int ks = 0; ks < 2; ++ks) {
                    bf16x8 bK = ld8(&lKb[row * 64 + (((ks * 4 + quad) ^ (row & 7)) * 8)]);
#pragma unroll
                    for (int mf = 0; mf < 2; ++mf)
                        s[mf][nt] = __builtin_amdgcn_mfma_f32_16x16x32_bf16(
                            aQ[mf][ks], bK, s[mf][nt], 0, 0, 0);
                }
            }
            __builtin_amdgcn_s_setprio(0);
            // p = exp(s); only the diagonal tile needs the causal mask
            if (kt0 + 63 > qw) {
#pragma unroll
                for (int mf = 0; mf < 2; ++mf)
#pragma unroll
                    for (int nt = 0; nt < 4; ++nt) {
                        const int colg = kt0 + nt * 16 + lrow;
#pragma unroll
                        for (int r = 0; r < 4; ++r) {
                            const int rowg = qw + mf * 16 + quad * 4 + r;
                            const float pv = (colg <= rowg) ? __expf(s[mf][nt][r]) : 0.f;
                            lP[wave][(mf * 16 + quad * 4 + r) * 68 + nt * 16 + lrow] = f2bf(pv);
                        }
                    }
            } else {
#pragma unroll
                for (int mf = 0; mf < 2; ++mf)
#pragma unroll
                    for (int nt = 0; nt < 4; ++nt)
#pragma unroll
                        for (int r = 0; r < 4; ++r)
                            lP[wave][(mf * 16 + quad * 4 + r) * 68 + nt * 16 + lrow] =
                                f2bf(__expf(s[mf][nt][r]));
            }
            bf16x8 aP[2][2];
#pragma unroll
            for (int mf = 0; mf < 2; ++mf)
#pragma unroll
                for (int ks = 0; ks < 2; ++ks)
                    aP[mf][ks] = ld8(&lP[wave][(mf * 16 + lrow) * 68 + ks * 32 + quad * 8]);
            __builtin_amdgcn_s_setprio(1);
#pragma unroll
            for (int mf = 0; mf < 2; ++mf)
#pragma unroll
                for (int ks = 0; ks < 2; ++ks)
                    lacc[mf] = __builtin_amdgcn_mfma_f32_16x16x32_bf16(
                        aP[mf][ks], bOnes, lacc[mf], 0, 0, 0);
#pragma unroll
            for (int dt = 0; dt < 4; ++dt) {
                const int row = dt * 16 + lrow;
#pragma unroll
                for (int ks = 0; ks < 2; ++ks) {
                    bf16x8 bV = ld8(&lVb[row * 64 + (((ks * 4 + quad) ^ (row & 7)) * 8)]);
#pragma unroll
                    for (int mf = 0; mf < 2; ++mf)
                        o[mf][dt] = __builtin_amdgcn_mfma_f32_16x16x32_bf16(
                            aP[mf][ks], bV, o[mf][dt], 0, 0, 0);
                }
            }
            __builtin_amdgcn_s_setprio(0);
        }
    }
#undef STAGE_T

    float inv[2][4];
#pragma unroll
    for (int mf = 0; mf < 2; ++mf)
#pragma unroll
        for (int r = 0; r < 4; ++r) inv[mf][r] = 1.0f / lacc[mf][r];
#pragma unroll
    for (int mf = 0; mf < 2; ++mf)
#pragma unroll
        for (int dt = 0; dt < 4; ++dt) {
            const int col = h * 64 + dt * 16 + lrow;
#pragma unroll
            for (int r = 0; r < 4; ++r) {
                const int trow = qw + mf * 16 + quad * 4 + r;
                ctx[((size_t)(b * 2048 + trow)) * 1024 + col] = f2bf(o[mf][dt][r] * inv[mf][r]);
            }
        }
}

extern "C" void kernel_launch(void* const* d_in, const int* in_sizes, int n_in,
                              void* d_out, int out_size, void* d_ws, size_t ws_size,
                              hipStream_t stream) {
    (void)in_sizes; (void)n_in; (void)out_size; (void)ws_size;
    const float* x    = (const float*)d_in[0];
    const float* wqkv = (const float*)d_in[1];
    const float* bqkv = (const float*)d_in[2];
    const float* wout = (const float*)d_in[3];
    const float* bout = (const float*)d_in[4];
    const int*   offp = (const int*)d_in[5];

    float* out   = (float*)d_out;
    float* cache = out + (size_t)2 * 2048 * 1024;   // 4,194,304 fp32 elems

    char* w = (char*)d_ws;
    float* tab            = (float*)w;          w += (size_t)2048 * 64 * sizeof(float);
    unsigned short* xb    = (unsigned short*)w; w += (size_t)4194304 * 2;
    unsigned short* wqkvT = (unsigned short*)w; w += (size_t)3072 * 1024 * 2;
    unsigned short* woutT = (unsigned short*)w; w += (size_t)1024 * 1024 * 2;
    unsigned short* qh    = (unsigned short*)w; w += (size_t)4194304 * 2;
    unsigned short* kh    = (unsigned short*)w; w += (size_t)4194304 * 2;
    unsigned short* vh    = (unsigned short*)w; w += (size_t)4194304 * 2;
    unsigned short* vt    = (unsigned short*)w; w += (size_t)4194304 * 2;
    unsigned short* ctx   = (unsigned short*)w; w += (size_t)4194304 * 2;

    k_ropetab<<<dim3(256), dim3(256), 0, stream>>>(tab, offp);
    // x fp32 [4096][1024] -> xb bf16
    k_cvt<<<dim3(2048), dim3(256), 0, stream>>>(x, xb);
    // Wqkv fp32 [1024][3072] -> WqkvT bf16 [3072][1024]
    k_transposeF2B<<<dim3(48, 16, 1), dim3(256), 0, stream>>>(wqkv, wqkvT, 1024, 3072);
    // Wout fp32 [1024][1024] -> WoutT bf16 [1024][1024]
    k_transposeF2B<<<dim3(16, 16, 1), dim3(256), 0, stream>>>(wout, woutT, 1024, 1024);
    // QKV projection + bias + RoPE + scatter: 256x256 tiles -> grid (3072/256, 4096/256)
    k_gemm<1><<<dim3(12, 16), dim3(512), 0, stream>>>(xb, wqkvT, bqkv, tab, qh, kh, vh, cache, nullptr);
    // V bf16 [bh][2048][64] -> Vt bf16 [bh][64][2048]
    k_transpose64<<<dim3(1, 32, 32), dim3(256), 0, stream>>>(vh, vt, 2048, 64);
    // flash attention -> ctx bf16 (merged triangle pair: 256 blocks x 8 waves, deep pipeline)
    k_attn<<<dim3(8, 16, 2), dim3(512), 0, stream>>>(qh, kh, vt, ctx);
    // out projection -> fp32 out: 64x64 tiles, grid (1024/64, 4096/64) = 1024 blocks
    k_gemm0<<<dim3(16, 64), dim3(256), 0, stream>>>(ctx, woutT, bout, out);
}